// Round 14
// baseline (66.632 us; speedup 1.0000x reference)
//
#include <hip/hip_runtime.h>
#include <math.h>

static constexpr int NPT = 98;
static constexpr float CSCALE_HALF = 0.155064240f;  // 0.5 * sqrt(log2(e)/15)

#if __has_builtin(__builtin_amdgcn_exp2f)
#define EXP2F(x) __builtin_amdgcn_exp2f(x)
#else
#define EXP2F(x) exp2f(x)
#endif
#if __has_builtin(__builtin_amdgcn_sqrtf)
#define SQRTF(x) __builtin_amdgcn_sqrtf(x)
#else
#define SQRTF(x) sqrtf(x)
#endif

typedef float v2f __attribute__((ext_vector_type(2)));
typedef float v4a __attribute__((ext_vector_type(4)));               // 16B aligned
typedef float v4fu __attribute__((ext_vector_type(4), aligned(8)));  // 8B aligned
typedef _Float16 h2 __attribute__((ext_vector_type(2)));
typedef _Float16 h4 __attribute__((ext_vector_type(4)));

#if __has_builtin(__builtin_amdgcn_fdot2)
#define FDOT2(a, b, c) __builtin_amdgcn_fdot2((a), (b), (c), false)
#else
#define FDOT2(a, b, c) fmaf((float)(a).x, (float)(b).x, fmaf((float)(a).y, (float)(b).y, (c)))
#endif

#if __has_builtin(__builtin_amdgcn_cvt_pkrtz)
#define PKRTZ(x, y) __builtin_bit_cast(h2, __builtin_amdgcn_cvt_pkrtz((x), (y)))
#else
static __device__ __forceinline__ h2 PKRTZ(float x, float y) {
    h2 r; r.x = (_Float16)x; r.y = (_Float16)y; return r;
}
#endif

// ---- Per-wave LDS slice (h4 slots {cx,cy,tx,ty}, f16, 8B each) ----
// Curves circular: M=2h segments + dup of first DUPN (c0:32, others:6).
//  c0: base   0, M=64, dup[64,96)          c4: base 162, M=14 -> [162,182)
//  c1: base  96, M=16, dup 6 -> [96,118)   c5: base 182, M=14 -> [182,202)
//  c2: base 118, M=16 -> [118,140)         c6: base 202, M=22 -> [202,230)
//  c3: base 140, M=16 -> [140,162)         c7: base 230, M=18 -> [230,254)
// Two-column circulant: lane holds cols {j, j+h}; a read at offset t serves
// class t (vs col j) and class h-t (vs col j+h). U = sum C(t) + 1/2 C(h);
// curve total = diag + 2U.
//
// Single dispatch, G12 pattern: per-block partial via 4-float LDS combine,
// then ONE atomicAdd(out) per block. No threadfence / counter / conditional-
// barrier epilogue — that heavyweight form reproducibly poisoned codegen to
// 24 VGPR (R10/R12). d_out zeroed per call by a 4-byte hipMemsetAsync.

// Staging LUT: a[6:0] point idx | isg bit7 | dst[15:8] | dup[23:16] (255=none)
struct SLut { unsigned v[192]; };
static constexpr SLut make_slut() {
    SLut L{};
    constexpr int A[8]  = {0, 33, 42, 51, 60, 68, 76, 88};
    constexpr int NS[8] = {32, 8, 8, 8, 7, 7, 11, 9};
    constexpr int BB[8] = {0, 96, 118, 140, 162, 182, 202, 230};
    int s = 0;
    for (int c = 0; c < 8; ++c) {
        int dupn = (c == 0) ? 32 : 6;
        for (int rel = 0; rel < 2 * NS[c]; ++rel, ++s) {
            bool isg = rel >= NS[c];
            int a = A[c] + (isg ? rel - NS[c] : rel);
            int dst = BB[c] + rel;
            int dup = (rel < dupn) ? (BB[c] + 2 * NS[c] + rel) : 255;
            L.v[s] = (unsigned)a | (isg ? 0x80u : 0u)
                   | ((unsigned)dst << 8) | ((unsigned)dup << 16);
        }
    }
    for (; s < 192; ++s) L.v[s] = 0u | (254u << 8) | (255u << 16);
    return L;
}
__constant__ SLut cSLUT = make_slut();

// Phase-B LUT: spOff[7:0] | h[11:8] | TA[14:12] | TB[17:15] | mm bit18
struct BLut { unsigned v[64]; };
static constexpr BLut make_blut() {
    BLut L{};
    constexpr int lo[8]   = {0, 8, 16, 24, 31, 38, 49, 58};
    constexpr int bs[8]   = {96, 118, 140, 162, 182, 202, 230, 202};
    constexpr int hh[8]   = {8, 8, 8, 7, 7, 11, 9, 11};
    constexpr int ta[8]   = {4, 4, 4, 3, 3, 5, 4, 0};
    constexpr int tb[8]   = {3, 3, 3, 3, 3, 5, 4, 0};
    constexpr int mmv[8]  = {1, 1, 1, 1, 1, 1, 1, 0};
    for (int g = 0; g < 8; ++g) {
        int hi = (g < 7) ? lo[g + 1] : 64;
        for (int l = lo[g]; l < hi; ++l) {
            int off = bs[g] + ((g < 7) ? (l - lo[g]) : 0);
            L.v[l] = (unsigned)off | ((unsigned)hh[g] << 8)
                   | ((unsigned)ta[g] << 12) | ((unsigned)tb[g] << 15)
                   | ((unsigned)mmv[g] << 18);
        }
    }
    return L;
}
__constant__ BLut cBLUT = make_blut();

__device__ __forceinline__ float wdt(h4 si, h4 sj) {
    h2 dc = si.xy - sj.xy;                         // v_pk_add_f16
    float d2 = FDOT2(dc, dc, 0.0f);                // v_dot2_f32_f16 (pre-scaled)
    float dt = FDOT2(si.zw, sj.zw, 0.0f);
    return EXP2F(-d2) * dt;
}

__global__ __launch_bounds__(256, 4)   // cap 128 VGPR: no spill, room for ILP
void lddmm_main(const float* __restrict__ pred, const float* __restrict__ gt,
                float* __restrict__ out, float invbatch) {
    __shared__ h4 sh[4][256];
    __shared__ float part[4];
    const int tid = threadIdx.x;
    const int wave = tid >> 6;
    const int lane = tid & 63;
    __builtin_assume(lane < 64);
    const int b = blockIdx.x * 4 + wave;

    const float* pf = pred + (size_t)b * (2 * NPT);
    const float* gf = gt + (size_t)b * (2 * NPT);
    const v2f* g2 = (const v2f*)gf;
    h4* sw = sh[wave];

    // eye-corner loads issued early (consumed at the very end)
    v2f e0 = g2[60];
    v2f e1 = g2[72];

    float diag = 0.0f;    // class-0: sum |tau|^2 (f32, exact)
    float accS = 0.0f;    // x1 bucket (c0 mirror C(32))
    float accA = 0.0f;    // x2 bucket, chain A
    float accB = 0.0f;    // x2 bucket, chain B
    float dsum = 0.0f;

    // ---- staging: 180 segments in f16 (+ wrap dups), 3 LUT-driven passes
    #pragma unroll
    for (int pass = 0; pass < 3; ++pass) {
        int s = lane + 64 * pass;
        if (s < 180) {    // folds away for pass 0/1
            unsigned e = cSLUT.v[s];
            int a = e & 0x7f;
            bool isg = (e & 0x80u) != 0;
            int dst = (int)((e >> 8) & 0xffu);
            int dup = (int)((e >> 16) & 0xffu);
            const float* src = isg ? gf : pf;
            v4fu q = *(const v4fu*)(src + 2 * a);   // {x0,y0,x1,y1}
            v2f c = (q.xy + q.zw) * CSCALE_HALF;
            v2f tau = q.zw - q.xy;
            if (isg) tau = -tau;
            diag = fmaf(tau.x, tau.x, diag);
            diag = fmaf(tau.y, tau.y, diag);
            h2 ch = PKRTZ(c.x, c.y);
            h2 th = PKRTZ(tau.x, tau.y);
            h4 v; v.x = ch.x; v.y = ch.y; v.z = th.x; v.w = th.y;
            sw[dst] = v;
            if (dup != 255) sw[dup] = v;            // circular dup
        }
    }

    // ---- landmark mean distance (f32, one float4 pass: 2 points/lane)
    if (lane < 49) {
        v4a p4 = *(const v4a*)(pf + 4 * lane);
        v4a g4 = *(const v4a*)(gf + 4 * lane);
        v2f d0 = p4.xy - g4.xy;
        v2f d1 = p4.zw - g4.zw;
        dsum = SQRTF(d0.x * d0.x + d0.y * d0.y)
             + SQRTF(d1.x * d1.x + d1.y * d1.y);
    }

    // wave-local LDS fence: this wave's ds_writes complete before its reads.
    asm volatile("s_waitcnt lgkmcnt(0)" ::: "memory");

    // ---- phase A: curve 0 (M=64, h=32), cols {lane, lane+32}
    {
        h4 sjA = sw[lane];
        h4 sjB = sw[lane + 32];
        #pragma unroll 8          // wide ILP: 8 ds_read_b64 in flight
        for (int t = 1; t <= 15; ++t) {
            h4 r = sw[lane + t];
            accA += wdt(r, sjA);
            accB += wdt(r, sjB);
        }
        { h4 r = sw[lane + 16]; accA += wdt(r, sjA); }  // t=16: sjA only
        accS += wdt(sjA, sjB);   // mirror: sum over 64 lanes = C(32) -> x1
    }

    // ---- phase B: curves c1..c7 (58 lanes), LUT-driven cols {jl, jl+h}
    {
        unsigned e = cBLUT.v[lane];
        const h4* sp = sw + (e & 0xffu);
        int h = (int)((e >> 8) & 0xfu);
        int TA = (int)((e >> 12) & 7u);
        int TB = (int)((e >> 15) & 7u);
        float mm = (e & (1u << 18)) ? 1.0f : 0.0f;
        h4 sjA = sp[0];
        h4 sjB = sp[h];
        accA = fmaf(mm, wdt(sjA, sjB), accA);   // mirror = 1/2 C(h) -> x2
        #pragma unroll
        for (int t = 1; t <= 5; ++t) {
            h4 u1 = sp[t];
            h4 u2 = sp[h + t];
            float mA = (t <= TA) ? 1.0f : 0.0f;
            float mB = (t <= TB) ? 1.0f : 0.0f;
            accA = fmaf(mA, wdt(u1, sjA) + wdt(u2, sjB), accA);  // C(t)
            accB = fmaf(mB, wdt(u1, sjB) + wdt(u2, sjA), accB);  // C(h-t)
        }
    }

    // curve total = diag + accS + 2*(accA+accB); combine with landmark term
    float v = 0.8f * dsum + 0.2f * (fmaf(2.0f, accA + accB, diag + accS));
    #pragma unroll
    for (int off = 32; off >= 1; off >>= 1) v += __shfl_xor(v, off, 64);

    if (lane == 0) {
        v2f de = e0 - e1;
        float eye = SQRTF(de.x * de.x + de.y * de.y);
        part[wave] = v / ((float)NPT * eye);
    }
    __syncthreads();

    // ---- G12 epilogue: one atomic per block
    if (tid == 0) {
        float blk = (part[0] + part[1]) + (part[2] + part[3]);
        atomicAdd(out, blk * invbatch);
    }
}

extern "C" void kernel_launch(void* const* d_in, const int* in_sizes, int n_in,
                              void* d_out, int out_size, void* d_ws, size_t ws_size,
                              hipStream_t stream) {
    const float* pred = (const float*)d_in[0];
    const float* gt = (const float*)d_in[1];
    float* out = (float*)d_out;
    const int batch = in_sizes[0] / (2 * NPT);

    hipMemsetAsync(out, 0, sizeof(float), stream);   // zero accumulator per call
    lddmm_main<<<batch / 4, 256, 0, stream>>>(pred, gt, out, 1.0f / (float)batch);
}

// Round 15
// 26.308 us; speedup vs baseline: 2.5327x; 2.5327x over previous
//
#include <hip/hip_runtime.h>
#include <math.h>

static constexpr int NPT = 98;
static constexpr float CSCALE_HALF = 0.155064240f;  // 0.5 * sqrt(log2(e)/15)

#if __has_builtin(__builtin_amdgcn_exp2f)
#define EXP2F(x) __builtin_amdgcn_exp2f(x)
#else
#define EXP2F(x) exp2f(x)
#endif
#if __has_builtin(__builtin_amdgcn_sqrtf)
#define SQRTF(x) __builtin_amdgcn_sqrtf(x)
#else
#define SQRTF(x) sqrtf(x)
#endif

typedef float v2f __attribute__((ext_vector_type(2)));
typedef float v4a __attribute__((ext_vector_type(4)));               // 16B aligned
typedef float v4fu __attribute__((ext_vector_type(4), aligned(8)));  // 8B aligned
typedef _Float16 h2 __attribute__((ext_vector_type(2)));
typedef _Float16 h4 __attribute__((ext_vector_type(4)));

#if __has_builtin(__builtin_amdgcn_fdot2)
#define FDOT2(a, b, c) __builtin_amdgcn_fdot2((a), (b), (c), false)
#else
#define FDOT2(a, b, c) fmaf((float)(a).x, (float)(b).x, fmaf((float)(a).y, (float)(b).y, (c)))
#endif

#if __has_builtin(__builtin_amdgcn_cvt_pkrtz)
#define PKRTZ(x, y) __builtin_bit_cast(h2, __builtin_amdgcn_cvt_pkrtz((x), (y)))
#else
static __device__ __forceinline__ h2 PKRTZ(float x, float y) {
    h2 r; r.x = (_Float16)x; r.y = (_Float16)y; return r;
}
#endif

// ---- Structure (R15): TWO elements per wave, fully interleaved ----
// Same circulant layout per element slice (h4 {cx,cy,tx,ty} f16):
//  c0: [0,96) (dup 32)  c1:[96,118) c2:[118,140) c3:[140,162) (dup 6 each)
//  c4:[162,182) c5:[182,202) c6:[202,230) c7:[230,254)
// Two-column circulant per curve: lane holds cols {j, j+h}; read at offset t
// serves class t (vs A) and class h-t (vs B). U = sum C(t) + 1/2 C(h).
//
// Each wave owns elements b0=2*wid, b1=2*wid+1 with separate LDS slices;
// every phase issues both elements' ops back-to-back -> 2 independent
// dependency chains per lane (ILP), halving stall time if latency-bound.
// All state explicitly _0/_1 suffixed (no runtime-indexed reg arrays).
// Two-kernel structure: fused reduction epilogues (atomic/fence) reproducibly
// poison codegen to 24-32 VGPR / low ILP (R10/R12/R14).

// Staging LUT: a[6:0] point idx | isg bit7 | dst[15:8] | dup[23:16] (255=none)
struct SLut { unsigned v[192]; };
static constexpr SLut make_slut() {
    SLut L{};
    constexpr int A[8]  = {0, 33, 42, 51, 60, 68, 76, 88};
    constexpr int NS[8] = {32, 8, 8, 8, 7, 7, 11, 9};
    constexpr int BB[8] = {0, 96, 118, 140, 162, 182, 202, 230};
    int s = 0;
    for (int c = 0; c < 8; ++c) {
        int dupn = (c == 0) ? 32 : 6;
        for (int rel = 0; rel < 2 * NS[c]; ++rel, ++s) {
            bool isg = rel >= NS[c];
            int a = A[c] + (isg ? rel - NS[c] : rel);
            int dst = BB[c] + rel;
            int dup = (rel < dupn) ? (BB[c] + 2 * NS[c] + rel) : 255;
            L.v[s] = (unsigned)a | (isg ? 0x80u : 0u)
                   | ((unsigned)dst << 8) | ((unsigned)dup << 16);
        }
    }
    for (; s < 192; ++s) L.v[s] = 0u | (254u << 8) | (255u << 16);
    return L;
}
__constant__ SLut cSLUT = make_slut();

// Phase-B LUT: spOff[7:0] | h[11:8] | TA[14:12] | TB[17:15] | mm bit18
struct BLut { unsigned v[64]; };
static constexpr BLut make_blut() {
    BLut L{};
    constexpr int lo[8]   = {0, 8, 16, 24, 31, 38, 49, 58};
    constexpr int bs[8]   = {96, 118, 140, 162, 182, 202, 230, 202};
    constexpr int hh[8]   = {8, 8, 8, 7, 7, 11, 9, 11};
    constexpr int ta[8]   = {4, 4, 4, 3, 3, 5, 4, 0};
    constexpr int tb[8]   = {3, 3, 3, 3, 3, 5, 4, 0};
    constexpr int mmv[8]  = {1, 1, 1, 1, 1, 1, 1, 0};
    for (int g = 0; g < 8; ++g) {
        int hi = (g < 7) ? lo[g + 1] : 64;
        for (int l = lo[g]; l < hi; ++l) {
            int off = bs[g] + ((g < 7) ? (l - lo[g]) : 0);
            L.v[l] = (unsigned)off | ((unsigned)hh[g] << 8)
                   | ((unsigned)ta[g] << 12) | ((unsigned)tb[g] << 15)
                   | ((unsigned)mmv[g] << 18);
        }
    }
    return L;
}
__constant__ BLut cBLUT = make_blut();

__device__ __forceinline__ float wdt(h4 si, h4 sj) {
    h2 dc = si.xy - sj.xy;                         // v_pk_add_f16
    float d2 = FDOT2(dc, dc, 0.0f);                // v_dot2_f32_f16 (pre-scaled)
    float dt = FDOT2(si.zw, sj.zw, 0.0f);
    return EXP2F(-d2) * dt;
}

__global__ __launch_bounds__(256, 4)   // cap 128 VGPR; est ~90-110 natural
void lddmm_main(const float* __restrict__ pred, const float* __restrict__ gt,
                float* __restrict__ ws) {
    __shared__ h4 sh[8][256];            // 2 slices per wave
    const int wave = threadIdx.x >> 6;
    const int lane = threadIdx.x & 63;
    __builtin_assume(lane < 64);
    const int wid = blockIdx.x * 4 + wave;
    const int b0 = 2 * wid;

    const float* pf0 = pred + (size_t)b0 * (2 * NPT);
    const float* gf0 = gt + (size_t)b0 * (2 * NPT);
    const float* pf1 = pf0 + 2 * NPT;
    const float* gf1 = gf0 + 2 * NPT;
    h4* sw0 = sh[2 * wave];
    h4* sw1 = sh[2 * wave + 1];

    // eye-corner loads issued early
    v2f e00 = ((const v2f*)gf0)[60];
    v2f e01 = ((const v2f*)gf0)[72];
    v2f e10 = ((const v2f*)gf1)[60];
    v2f e11 = ((const v2f*)gf1)[72];

    float diag_0 = 0.0f, diag_1 = 0.0f;
    float accS_0 = 0.0f, accS_1 = 0.0f;
    float accA_0 = 0.0f, accA_1 = 0.0f;
    float accB_0 = 0.0f, accB_1 = 0.0f;
    float dsum_0 = 0.0f, dsum_1 = 0.0f;

    // ---- staging: both elements interleaved, 3 LUT-driven passes
    #pragma unroll
    for (int pass = 0; pass < 3; ++pass) {
        int s = lane + 64 * pass;
        if (s < 180) {
            unsigned e = cSLUT.v[s];
            int a = e & 0x7f;
            bool isg = (e & 0x80u) != 0;
            int dst = (int)((e >> 8) & 0xffu);
            int dup = (int)((e >> 16) & 0xffu);
            const float* src0 = isg ? gf0 : pf0;
            const float* src1 = isg ? gf1 : pf1;
            v4fu q0 = *(const v4fu*)(src0 + 2 * a);
            v4fu q1 = *(const v4fu*)(src1 + 2 * a);
            v2f c0 = (q0.xy + q0.zw) * CSCALE_HALF;
            v2f c1 = (q1.xy + q1.zw) * CSCALE_HALF;
            v2f t0 = q0.zw - q0.xy;
            v2f t1 = q1.zw - q1.xy;
            if (isg) { t0 = -t0; t1 = -t1; }
            diag_0 = fmaf(t0.x, t0.x, diag_0);
            diag_0 = fmaf(t0.y, t0.y, diag_0);
            diag_1 = fmaf(t1.x, t1.x, diag_1);
            diag_1 = fmaf(t1.y, t1.y, diag_1);
            h2 ch0 = PKRTZ(c0.x, c0.y), th0 = PKRTZ(t0.x, t0.y);
            h2 ch1 = PKRTZ(c1.x, c1.y), th1 = PKRTZ(t1.x, t1.y);
            h4 v0; v0.x = ch0.x; v0.y = ch0.y; v0.z = th0.x; v0.w = th0.y;
            h4 v1; v1.x = ch1.x; v1.y = ch1.y; v1.z = th1.x; v1.w = th1.y;
            sw0[dst] = v0;
            sw1[dst] = v1;
            if (dup != 255) { sw0[dup] = v0; sw1[dup] = v1; }
        }
    }

    // ---- landmark mean distance (2 points/lane, both elements)
    if (lane < 49) {
        v4a p40 = *(const v4a*)(pf0 + 4 * lane);
        v4a g40 = *(const v4a*)(gf0 + 4 * lane);
        v4a p41 = *(const v4a*)(pf1 + 4 * lane);
        v4a g41 = *(const v4a*)(gf1 + 4 * lane);
        v2f a0 = p40.xy - g40.xy, a1 = p40.zw - g40.zw;
        v2f b0d = p41.xy - g41.xy, b1d = p41.zw - g41.zw;
        dsum_0 = SQRTF(a0.x * a0.x + a0.y * a0.y)
               + SQRTF(a1.x * a1.x + a1.y * a1.y);
        dsum_1 = SQRTF(b0d.x * b0d.x + b0d.y * b0d.y)
               + SQRTF(b1d.x * b1d.x + b1d.y * b1d.y);
    }

    // wave-local LDS fence
    asm volatile("s_waitcnt lgkmcnt(0)" ::: "memory");

    // ---- phase A: curve 0 (M=64, h=32), both elements interleaved
    {
        h4 sjA0 = sw0[lane], sjB0 = sw0[lane + 32];
        h4 sjA1 = sw1[lane], sjB1 = sw1[lane + 32];
        #pragma unroll 4          // 8 b64 reads in flight (4 iter x 2 elems)
        for (int t = 1; t <= 15; ++t) {
            h4 r0 = sw0[lane + t];
            h4 r1 = sw1[lane + t];
            accA_0 += wdt(r0, sjA0);
            accA_1 += wdt(r1, sjA1);
            accB_0 += wdt(r0, sjB0);
            accB_1 += wdt(r1, sjB1);
        }
        {
            h4 r0 = sw0[lane + 16];
            h4 r1 = sw1[lane + 16];
            accA_0 += wdt(r0, sjA0);
            accA_1 += wdt(r1, sjA1);
        }
        accS_0 += wdt(sjA0, sjB0);
        accS_1 += wdt(sjA1, sjB1);
    }

    // ---- phase B: curves c1..c7, LUT-driven, both elements interleaved
    {
        unsigned e = cBLUT.v[lane];
        int off = (int)(e & 0xffu);
        int h = (int)((e >> 8) & 0xfu);
        int TA = (int)((e >> 12) & 7u);
        int TB = (int)((e >> 15) & 7u);
        float mm = (e & (1u << 18)) ? 1.0f : 0.0f;
        const h4* sp0 = sw0 + off;
        const h4* sp1 = sw1 + off;
        h4 sjA0 = sp0[0], sjB0 = sp0[h];
        h4 sjA1 = sp1[0], sjB1 = sp1[h];
        accA_0 = fmaf(mm, wdt(sjA0, sjB0), accA_0);
        accA_1 = fmaf(mm, wdt(sjA1, sjB1), accA_1);
        #pragma unroll
        for (int t = 1; t <= 5; ++t) {
            h4 u10 = sp0[t], u20 = sp0[h + t];
            h4 u11 = sp1[t], u21 = sp1[h + t];
            float mA = (t <= TA) ? 1.0f : 0.0f;
            float mB = (t <= TB) ? 1.0f : 0.0f;
            accA_0 = fmaf(mA, wdt(u10, sjA0) + wdt(u20, sjB0), accA_0);
            accA_1 = fmaf(mA, wdt(u11, sjA1) + wdt(u21, sjB1), accA_1);
            accB_0 = fmaf(mB, wdt(u10, sjB0) + wdt(u20, sjA0), accB_0);
            accB_1 = fmaf(mB, wdt(u11, sjB1) + wdt(u21, sjA1), accB_1);
        }
    }

    // combine + two wave reductions (independent chains)
    float v0 = 0.8f * dsum_0 + 0.2f * (fmaf(2.0f, accA_0 + accB_0, diag_0 + accS_0));
    float v1 = 0.8f * dsum_1 + 0.2f * (fmaf(2.0f, accA_1 + accB_1, diag_1 + accS_1));
    #pragma unroll
    for (int off = 32; off >= 1; off >>= 1) {
        v0 += __shfl_xor(v0, off, 64);
        v1 += __shfl_xor(v1, off, 64);
    }

    if (lane == 0) {
        v2f de0 = e00 - e01;
        v2f de1 = e10 - e11;
        float eye0 = SQRTF(de0.x * de0.x + de0.y * de0.y);
        float eye1 = SQRTF(de1.x * de1.x + de1.y * de1.y);
        ws[b0]     = v0 / ((float)NPT * eye0);
        ws[b0 + 1] = v1 / ((float)NPT * eye1);
    }
}

__global__ __launch_bounds__(1024)
void lddmm_reduce(const float* __restrict__ ws, float* __restrict__ out,
                  int n4, float invbatch) {
    __shared__ float sm[1024];
    const int t = threadIdx.x;
    const float4* w4 = (const float4*)ws;
    float s = 0.0f;
    for (int i = t; i < n4; i += 1024) {
        float4 v = w4[i];
        s += (v.x + v.y) + (v.z + v.w);
    }
    sm[t] = s;
    __syncthreads();
    for (int off = 512; off >= 1; off >>= 1) {
        if (t < off) sm[t] += sm[t + off];
        __syncthreads();
    }
    if (t == 0) out[0] = sm[0] * invbatch;
}

extern "C" void kernel_launch(void* const* d_in, const int* in_sizes, int n_in,
                              void* d_out, int out_size, void* d_ws, size_t ws_size,
                              hipStream_t stream) {
    const float* pred = (const float*)d_in[0];
    const float* gt = (const float*)d_in[1];
    float* out = (float*)d_out;
    float* ws = (float*)d_ws;
    const int batch = in_sizes[0] / (2 * NPT);

    const int nblk = batch / 8;   // 2 elems/wave, 4 waves/block
    lddmm_main<<<nblk, 256, 0, stream>>>(pred, gt, ws);
    lddmm_reduce<<<1, 1024, 0, stream>>>(ws, out, batch / 4, 1.0f / (float)batch);
}